// Round 10
// baseline (344.214 us; speedup 1.0000x reference)
//
#include <hip/hip_runtime.h>
#include <hip/hip_fp16.h>
#include <math.h>
#include <string.h>

constexpr int D = 128;

struct __align__(16) H8 { __half2 h[4]; };
struct __align__(8)  H4 { __half2 a, b; };

typedef _Float16 half8  __attribute__((ext_vector_type(8)));
typedef float   floatx4 __attribute__((ext_vector_type(4)));
typedef int     i32x4   __attribute__((ext_vector_type(4)));

// ---- non-temporal helpers: ONLY for stream-once data off the critical chain ----
template <typename T>
__device__ __forceinline__ T ld_nt(const T* p) {
  i32x4 v = __builtin_nontemporal_load((const i32x4*)p);
  T r; memcpy(&r, &v, 16); return r;
}
__device__ __forceinline__ void st_nt8(void* p, float2 v) {
  long long t; memcpy(&t, &v, 8);
  __builtin_nontemporal_store(t, (long long*)p);
}

// ---------------- preprocessing ----------------

__device__ __forceinline__ int detect64(const int* __restrict__ ei) {
  int z = 0;
#pragma unroll
  for (int i = 0; i < 8; ++i) z |= ei[2 * i + 1];
  return (z == 0) ? 1 : 0;
}

__device__ __forceinline__ void load_edge(const int* __restrict__ ei, int e, int nE,
                                          int m64, int n, int& r, int& c) {
  if (m64) { r = ei[2 * (size_t)e]; c = ei[2 * ((size_t)nE + e)]; }
  else     { r = ei[(size_t)e];     c = ei[(size_t)nE + e]; }
  r = min(max(r, 0), n - 1);
  c = min(max(c, 0), n - 1);
}

// blocks [0,3): transpose W1/W2/W3 fp32 [k][n] -> Wt fp16 [n][k]. blocks [3..): zero cnt.
__global__ void k_init(const float* __restrict__ W1, const float* __restrict__ W2,
                       const float* __restrict__ W3, __half* __restrict__ Wt,
                       int* __restrict__ cnt, int n) {
  __shared__ float s[128][129];
  int tid = threadIdx.x;
  if (blockIdx.x >= 3) {
    int i = (blockIdx.x - 3) * 256 + tid;
    if (i < n) cnt[i] = 0;
    return;
  }
  const float* W = blockIdx.x == 0 ? W1 : (blockIdx.x == 1 ? W2 : W3);
  __half* o = Wt + (size_t)blockIdx.x * D * D;
#pragma unroll
  for (int i = 0; i < 16; ++i) {
    int flat = i * 1024 + tid * 4;
    int k = flat >> 7;
    int nn = flat & 127;
    float4 v = *(const float4*)(W + (size_t)k * D + nn);
    s[k][nn] = v.x; s[k][nn + 1] = v.y; s[k][nn + 2] = v.z; s[k][nn + 3] = v.w;
  }
  __syncthreads();
#pragma unroll
  for (int i = 0; i < 8; ++i) {
    int flat = i * 256 + tid;
    int nn = flat >> 4;
    int k0 = (flat & 15) * 8;
    H8 hv;
#pragma unroll
    for (int t = 0; t < 4; ++t)
      hv.h[t] = __floats2half2_rn(s[k0 + 2 * t][nn], s[k0 + 2 * t + 1][nn]);
    *(H8*)(o + (size_t)nn * D + k0) = hv;
  }
}

// ONE atomic per edge; packed (r<<16)|c; rank stored for atomic-free fill.
__global__ void k_pos(const int* __restrict__ ei, int* __restrict__ cnt,
                      unsigned int* __restrict__ rcp, int* __restrict__ pos,
                      int nE, int n) {
  int e = blockIdx.x * blockDim.x + threadIdx.x;
  if (e >= nE) return;
  int m64 = detect64(ei);
  int r, c;
  load_edge(ei, e, nE, m64, n, r, c);
  rcp[e] = ((unsigned int)r << 16) | (unsigned int)c;
  pos[e] = atomicAdd(&cnt[c], 1);
}

// Single-block exclusive scan: 1024 threads, wave-shuffle scan + carried prefix.
__global__ __launch_bounds__(1024) void k_scan(const int* __restrict__ cnt,
                                               int* __restrict__ offs, int n, int nE) {
  __shared__ int wsx[16];
  __shared__ int tot;
  const int t = threadIdx.x;
  const int lane = t & 63, wid = t >> 6;
  int carry = 0;
  for (int base = 0; base < n; base += 1024) {
    int i = base + t;
    int v = (i < n) ? cnt[i] : 0;
    int s = v;
#pragma unroll
    for (int d = 1; d < 64; d <<= 1) {
      int x = __shfl_up(s, d, 64);
      if (lane >= d) s += x;
    }
    if (lane == 63) wsx[wid] = s;
    __syncthreads();
    if (t < 16) {
      int ws = wsx[t];
      int ss = ws;
#pragma unroll
      for (int d = 1; d < 16; d <<= 1) {
        int x = __shfl_up(ss, d, 16);
        if (t >= d) ss += x;
      }
      wsx[t] = ss - ws;            // exclusive wave offset
      if (t == 15) tot = ss;       // tile total
    }
    __syncthreads();
    if (i < n) offs[i] = carry + wsx[wid] + (s - v);
    carry += tot;
    __syncthreads();               // wsx/tot reused next tile
  }
  if (t == 0) offs[n] = nE;
}

// Atomic-free CSR fill writing the FINAL packed edge record: (src<<16) | fp16(w).
// (dinv[src] is folded into the GEMM epilogue, so no dinv needed here.)
__global__ void k_fill(const unsigned int* __restrict__ rcp, const int* __restrict__ pos,
                       const float* __restrict__ w, const int* __restrict__ offs,
                       unsigned int* __restrict__ ecf2, int nE) {
  int e = blockIdx.x * blockDim.x + threadIdx.x;
  if (e >= nE) return;
  unsigned int p = rcp[e];
  int idx = offs[p & 0xffffu] + pos[e];
  ecf2[idx] = (p & 0xffff0000u) |
              (unsigned int)__half_as_ushort(__float2half_rn(w[e]));
}

// deg[c] = 1 (self loop) + sum fp16(w) over CSR row; dinv = rsqrt(deg).
__global__ void k_degdinv(const unsigned int* __restrict__ ecf2, const int* __restrict__ offs,
                          float* __restrict__ dinv, int n) {
  int i = blockIdx.x * blockDim.x + threadIdx.x;
  if (i >= n) return;
  float s = 1.0f;
  int e1 = offs[i + 1];
  for (int e = offs[i]; e < e1; ++e)
    s += __half2float(__ushort_as_half((unsigned short)(ecf2[e] & 0xffffu)));
  dinv[i] = rsqrtf(s);
}

// ---------------- MFMA GEMM: Z(chunk layout) = half( dinv[node] * (act(A) @ W) ) ----------------
// Z layout: Z[chunk][n][32] halves, chunk = feature>>5.
template <int ACT>
__device__ __forceinline__ float act_f(float x) {
  if (ACT == 1) return x > 0.f ? x : expm1f(x);
  if (ACT == 2) return 0.5f * x * (1.0f + erff(x * 0.70710678118654752440f));
  return x;
}

template <int ACT, typename AT>
__global__ __launch_bounds__(256) void k_gemm(const AT* __restrict__ A,
                                              const __half* __restrict__ Wt,
                                              const float* __restrict__ dinv,
                                              __half* __restrict__ Z, int n) {
  const int wave = threadIdx.x >> 6;
  const int lane = threadIdx.x & 63;
  const int np = lane & 15;
  const int quad = lane >> 4;
  const int node = blockIdx.x * 64 + wave * 16 + np;
  const int nc = min(node, n - 1);

  half8 b[4];
#pragma unroll
  for (int s = 0; s < 4; ++s) {
    if constexpr (sizeof(AT) == 4) {
      // fp32 x: streamed once, nt-load keeps L2 for Z
      const float* ap = (const float*)A + (size_t)nc * D + s * 32 + quad * 8;
      float4 v0 = ld_nt((const float4*)ap);
      float4 v1 = ld_nt((const float4*)(ap + 4));
      b[s][0] = (_Float16)act_f<ACT>(v0.x); b[s][1] = (_Float16)act_f<ACT>(v0.y);
      b[s][2] = (_Float16)act_f<ACT>(v0.z); b[s][3] = (_Float16)act_f<ACT>(v0.w);
      b[s][4] = (_Float16)act_f<ACT>(v1.x); b[s][5] = (_Float16)act_f<ACT>(v1.y);
      b[s][6] = (_Float16)act_f<ACT>(v1.z); b[s][7] = (_Float16)act_f<ACT>(v1.w);
    } else {
      half8 raw = *(const half8*)((const __half*)A + ((size_t)s * n + nc) * 32 + quad * 8);
#pragma unroll
      for (int t = 0; t < 8; ++t)
        b[s][t] = (_Float16)act_f<ACT>((float)raw[t]);
    }
  }

  floatx4 acc[8];
#pragma unroll
  for (int mt = 0; mt < 8; ++mt) acc[mt] = (floatx4){0.f, 0.f, 0.f, 0.f};

#pragma unroll
  for (int mt = 0; mt < 8; ++mt) {
#pragma unroll
    for (int s = 0; s < 4; ++s) {
      half8 a = *(const half8*)(Wt + (size_t)(mt * 16 + np) * D + s * 32 + quad * 8);
      acc[mt] = __builtin_amdgcn_mfma_f32_16x16x32_f16(a, b[s], acc[mt], 0, 0, 0);
    }
  }

  if (node < n) {
    float dv = dinv[node];   // fold dinv[src] into Z so edge coef is just fp16(w)
#pragma unroll
    for (int mt = 0; mt < 8; ++mt) {
      H4 hv;
      hv.a = __floats2half2_rn(dv * acc[mt][0], dv * acc[mt][1]);
      hv.b = __floats2half2_rn(dv * acc[mt][2], dv * acc[mt][3]);
      int f0 = mt * 16 + quad * 4;
      *(H4*)(Z + ((size_t)(f0 >> 5) * n + node) * 32 + (f0 & 31)) = hv;
    }
  }
}

// -------- aggregation: OUT[c] = dc*( sum w*Z[r] + Z[c] ) + b --------
// 16 lanes/node: 4 edge-subs x 4 j-lanes (16B each). One 64B line per gather.
// chunk = blockIdx & 3 keeps the per-XCD gather working set at one 3.2MB region.
__device__ __forceinline__ void fmacc8(float* acc, float c, const H8& y) {
  float2 f;
  f = __half22float2(y.h[0]); acc[0] += c * f.x; acc[1] += c * f.y;
  f = __half22float2(y.h[1]); acc[2] += c * f.x; acc[3] += c * f.y;
  f = __half22float2(y.h[2]); acc[4] += c * f.x; acc[5] += c * f.y;
  f = __half22float2(y.h[3]); acc[6] += c * f.x; acc[7] += c * f.y;
}

__device__ __forceinline__ float cdecode(unsigned int u) {
  return __half2float(__ushort_as_half((unsigned short)(u & 0xffffu)));
}

template <int PRELU, typename OutT>
__global__ __launch_bounds__(256) void k_agg(const __half* __restrict__ Z,
                                             const int* __restrict__ offs,
                                             const unsigned int* __restrict__ ecf2,
                                             const float* __restrict__ dinv,
                                             const float* __restrict__ bias,
                                             const float* __restrict__ pw,
                                             OutT* __restrict__ OUT, int n) {
  const int chunk = blockIdx.x & 3;
  const int t = threadIdx.x;
  const int node = (blockIdx.x >> 2) * 16 + (t >> 4);
  const int sub = (t >> 2) & 3;   // 4-way edge split
  const int j = t & 3;            // 16B piece of the 64B chunk
  if (node >= n) return;
  const __half* Zc = Z + (size_t)chunk * n * 32;
  float acc[8] = {0.f, 0.f, 0.f, 0.f, 0.f, 0.f, 0.f, 0.f};
  if (sub == 0) {                 // self term: coefficient 1 (dinv folded into Z)
    H8 zs = *(const H8*)(Zc + (size_t)node * 32 + j * 8);
    fmacc8(acc, 1.0f, zs);
  }
  int e0 = offs[node], e1 = offs[node + 1];
  int e = e0 + sub;
  for (; e + 12 < e1; e += 16) {  // 4 gathers in flight
    unsigned int u0 = ecf2[e],     u1 = ecf2[e + 4];
    unsigned int u2 = ecf2[e + 8], u3 = ecf2[e + 12];
    H8 z0 = *(const H8*)(Zc + (size_t)(u0 >> 16) * 32 + j * 8);
    H8 z1 = *(const H8*)(Zc + (size_t)(u1 >> 16) * 32 + j * 8);
    H8 z2 = *(const H8*)(Zc + (size_t)(u2 >> 16) * 32 + j * 8);
    H8 z3 = *(const H8*)(Zc + (size_t)(u3 >> 16) * 32 + j * 8);
    fmacc8(acc, cdecode(u0), z0);
    fmacc8(acc, cdecode(u1), z1);
    fmacc8(acc, cdecode(u2), z2);
    fmacc8(acc, cdecode(u3), z3);
  }
  for (; e + 4 < e1; e += 8) {    // 2 in flight (common case)
    unsigned int u0 = ecf2[e], u1 = ecf2[e + 4];
    H8 z0 = *(const H8*)(Zc + (size_t)(u0 >> 16) * 32 + j * 8);
    H8 z1 = *(const H8*)(Zc + (size_t)(u1 >> 16) * 32 + j * 8);
    fmacc8(acc, cdecode(u0), z0);
    fmacc8(acc, cdecode(u1), z1);
  }
  for (; e < e1; e += 4) {
    unsigned int u = ecf2[e];
    H8 z = *(const H8*)(Zc + (size_t)(u >> 16) * 32 + j * 8);
    fmacc8(acc, cdecode(u), z);
  }
  // combine 4 subs: lanes differ in bits 2..3
#pragma unroll
  for (int i = 0; i < 8; ++i) {
    acc[i] += __shfl_xor(acc[i], 4, 64);
    acc[i] += __shfl_xor(acc[i], 8, 64);
  }
  // each (sub,j) lane writes 2 features: chunk*32 + j*8 + sub*2 .. +1
  float dc = dinv[node];
  const float* bp = bias + chunk * 32 + j * 8 + sub * 2;
  float o0 = dc * acc[sub * 2 + 0] + bp[0];
  float o1 = dc * acc[sub * 2 + 1] + bp[1];
  if (PRELU) {
    float wv = *pw;
    o0 = o0 >= 0.f ? o0 : wv * o0;
    o1 = o1 >= 0.f ? o1 : wv * o1;
  }
  if constexpr (sizeof(OutT) == 4) {
    st_nt8((float*)OUT + (size_t)node * D + chunk * 32 + j * 8 + sub * 2,
           make_float2(o0, o1));
  } else {
    *(__half2*)((__half*)OUT + ((size_t)chunk * n + node) * 32 + j * 8 + sub * 2) =
        __floats2half2_rn(o0, o1);
  }
}

// ---------------- launch ----------------
extern "C" void kernel_launch(void* const* d_in, const int* in_sizes, int n_in,
                              void* d_out, int out_size, void* d_ws, size_t ws_size,
                              hipStream_t stream) {
  const float* x  = (const float*)d_in[0];
  const int*   ei = (const int*)d_in[1];
  const float* w  = (const float*)d_in[2];
  const float* W1 = (const float*)d_in[3];
  const float* b1 = (const float*)d_in[4];
  const float* W2 = (const float*)d_in[5];
  const float* b2 = (const float*)d_in[6];
  const float* W3 = (const float*)d_in[7];
  const float* b3 = (const float*)d_in[8];
  const float* pw = (const float*)d_in[9];
  const int N = in_sizes[0] / D;
  const int E = in_sizes[2];
  float* out = (float*)d_out;

  char* wsb = (char*)d_ws;
  size_t off = 0;
  auto alloc = [&](size_t bytes) {
    void* p = wsb + off;
    off = (off + bytes + 255) & ~(size_t)255;
    return p;
  };
  float*        dinv = (float*)alloc((size_t)N * 4);
  int*          cnt  = (int*)alloc((size_t)N * 4);
  int*          offs = (int*)alloc((size_t)(N + 1) * 4);
  unsigned int* ecf2 = (unsigned int*)alloc((size_t)E * 4);
  __half*       Wt   = (__half*)alloc((size_t)3 * D * D * 2);
  __half*       Z    = (__half*)alloc((size_t)N * D * 2);
  __half*       h    = (__half*)alloc((size_t)N * D * 2);
  // transient buffers aliased into Z (dead before first GEMM writes Z): 8B/edge < N*D*2
  unsigned int* rcp  = (unsigned int*)Z;
  int*          pos  = (int*)((char*)Z + (size_t)E * 4);

  const int nb = (N + 255) / 256;
  const int eb = (E + 255) / 256;

  hipLaunchKernelGGL(k_init,    dim3(3 + nb), dim3(256), 0, stream, W1, W2, W3, Wt, cnt, N);
  hipLaunchKernelGGL(k_pos,     dim3(eb), dim3(256), 0, stream, ei, cnt, rcp, pos, E, N);
  hipLaunchKernelGGL(k_scan,    dim3(1),  dim3(1024), 0, stream, cnt, offs, N, E);
  hipLaunchKernelGGL(k_fill,    dim3(eb), dim3(256), 0, stream, rcp, pos, w, offs, ecf2, E);
  hipLaunchKernelGGL(k_degdinv, dim3(nb), dim3(256), 0, stream, ecf2, offs, dinv, N);

  const int gb = (N + 63) / 64;
  const int ab = 4 * ((N + 15) / 16);

  hipLaunchKernelGGL((k_gemm<0, float>),  dim3(gb), dim3(256), 0, stream, x, Wt,             dinv, Z, N);
  hipLaunchKernelGGL((k_agg<0, __half>),  dim3(ab), dim3(256), 0, stream, Z, offs, ecf2, dinv, b1, pw, h, N);
  hipLaunchKernelGGL((k_gemm<1, __half>), dim3(gb), dim3(256), 0, stream, h, Wt + D * D,     dinv, Z, N);
  hipLaunchKernelGGL((k_agg<0, __half>),  dim3(ab), dim3(256), 0, stream, Z, offs, ecf2, dinv, b2, pw, h, N);
  hipLaunchKernelGGL((k_gemm<2, __half>), dim3(gb), dim3(256), 0, stream, h, Wt + 2 * D * D, dinv, Z, N);
  hipLaunchKernelGGL((k_agg<1, float>),   dim3(ab), dim3(256), 0, stream, Z, offs, ecf2, dinv, b3, pw, out, N);
}

// Round 11
// 305.828 us; speedup vs baseline: 1.1255x; 1.1255x over previous
//
#include <hip/hip_runtime.h>
#include <hip/hip_fp16.h>
#include <math.h>
#include <string.h>

constexpr int D = 128;

struct __align__(16) H8 { __half2 h[4]; };
struct __align__(8)  H4 { __half2 a, b; };

typedef _Float16 half8  __attribute__((ext_vector_type(8)));
typedef float   floatx4 __attribute__((ext_vector_type(4)));
typedef int     i32x4   __attribute__((ext_vector_type(4)));

// ---- non-temporal helpers: ONLY for stream-once data off the critical chain ----
template <typename T>
__device__ __forceinline__ T ld_nt(const T* p) {
  i32x4 v = __builtin_nontemporal_load((const i32x4*)p);
  T r; memcpy(&r, &v, 16); return r;
}
__device__ __forceinline__ void st_nt8(void* p, float2 v) {
  long long t; memcpy(&t, &v, 8);
  __builtin_nontemporal_store(t, (long long*)p);
}

// ---------------- preprocessing ----------------

__device__ __forceinline__ int detect64(const int* __restrict__ ei) {
  int z = 0;
#pragma unroll
  for (int i = 0; i < 8; ++i) z |= ei[2 * i + 1];
  return (z == 0) ? 1 : 0;
}

__device__ __forceinline__ void load_edge(const int* __restrict__ ei, int e, int nE,
                                          int m64, int n, int& r, int& c) {
  if (m64) { r = ei[2 * (size_t)e]; c = ei[2 * ((size_t)nE + e)]; }
  else     { r = ei[(size_t)e];     c = ei[(size_t)nE + e]; }
  r = min(max(r, 0), n - 1);
  c = min(max(c, 0), n - 1);
}

// blocks [0,3): transpose W1/W2/W3 fp32 [k][n] -> Wt fp16 [n][k]. blocks [3..): zero cnt.
__global__ void k_init(const float* __restrict__ W1, const float* __restrict__ W2,
                       const float* __restrict__ W3, __half* __restrict__ Wt,
                       int* __restrict__ cnt, int n) {
  __shared__ float s[128][129];
  int tid = threadIdx.x;
  if (blockIdx.x >= 3) {
    int i = (blockIdx.x - 3) * 256 + tid;
    if (i < n) cnt[i] = 0;
    return;
  }
  const float* W = blockIdx.x == 0 ? W1 : (blockIdx.x == 1 ? W2 : W3);
  __half* o = Wt + (size_t)blockIdx.x * D * D;
#pragma unroll
  for (int i = 0; i < 16; ++i) {
    int flat = i * 1024 + tid * 4;
    int k = flat >> 7;
    int nn = flat & 127;
    float4 v = *(const float4*)(W + (size_t)k * D + nn);
    s[k][nn] = v.x; s[k][nn + 1] = v.y; s[k][nn + 2] = v.z; s[k][nn + 3] = v.w;
  }
  __syncthreads();
#pragma unroll
  for (int i = 0; i < 8; ++i) {
    int flat = i * 256 + tid;
    int nn = flat >> 4;
    int k0 = (flat & 15) * 8;
    H8 hv;
#pragma unroll
    for (int t = 0; t < 4; ++t)
      hv.h[t] = __floats2half2_rn(s[k0 + 2 * t][nn], s[k0 + 2 * t + 1][nn]);
    *(H8*)(o + (size_t)nn * D + k0) = hv;
  }
}

// ONE atomic per edge; packed (r<<16)|c; rank stored for atomic-free fill.
__global__ void k_pos(const int* __restrict__ ei, int* __restrict__ cnt,
                      unsigned int* __restrict__ rcp, int* __restrict__ pos,
                      int nE, int n) {
  int e = blockIdx.x * blockDim.x + threadIdx.x;
  if (e >= nE) return;
  int m64 = detect64(ei);
  int r, c;
  load_edge(ei, e, nE, m64, n, r, c);
  rcp[e] = ((unsigned int)r << 16) | (unsigned int)c;
  pos[e] = atomicAdd(&cnt[c], 1);
}

// Parallel 3-kernel exclusive scan (196 blocks; k_scan single-block was 47us - serialized).
__global__ void k_scan1(const int* __restrict__ cnt, int* __restrict__ offs,
                        int* __restrict__ bsum, int n) {
  __shared__ int s[256];
  int t = threadIdx.x;
  int i = blockIdx.x * 256 + t;
  int v = (i < n) ? cnt[i] : 0;
  s[t] = v;
  __syncthreads();
  for (int off = 1; off < 256; off <<= 1) {
    int x = 0;
    if (t >= off) x = s[t - off];
    __syncthreads();
    if (t >= off) s[t] += x;
    __syncthreads();
  }
  if (i < n) offs[i] = s[t] - v;
  if (t == 255) bsum[blockIdx.x] = s[255];
}

__global__ void k_scan2(const int* __restrict__ bsum, int* __restrict__ boff, int nb) {
  __shared__ int s[256];
  int t = threadIdx.x;
  int v = (t < nb) ? bsum[t] : 0;
  s[t] = v;
  __syncthreads();
  for (int off = 1; off < 256; off <<= 1) {
    int x = 0;
    if (t >= off) x = s[t - off];
    __syncthreads();
    if (t >= off) s[t] += x;
    __syncthreads();
  }
  if (t < nb) boff[t] = s[t] - v;
}

__global__ void k_scan3(int* __restrict__ offs, const int* __restrict__ boff, int n, int nE) {
  int i = blockIdx.x * 256 + threadIdx.x;
  if (i < n) offs[i] += boff[blockIdx.x];
  if (i == 0) offs[n] = nE;
}

// Atomic-free CSR fill writing the FINAL packed edge record: (src<<16) | fp16(w).
__global__ void k_fill(const unsigned int* __restrict__ rcp, const int* __restrict__ pos,
                       const float* __restrict__ w, const int* __restrict__ offs,
                       unsigned int* __restrict__ ecf2, int nE) {
  int e = blockIdx.x * blockDim.x + threadIdx.x;
  if (e >= nE) return;
  unsigned int p = rcp[e];
  int idx = offs[p & 0xffffu] + pos[e];
  ecf2[idx] = (p & 0xffff0000u) |
              (unsigned int)__half_as_ushort(__float2half_rn(w[e]));
}

// deg[c] = 1 (self loop) + sum fp16(w) over CSR row; dinv = rsqrt(deg).
__global__ void k_degdinv(const unsigned int* __restrict__ ecf2, const int* __restrict__ offs,
                          float* __restrict__ dinv, int n) {
  int i = blockIdx.x * blockDim.x + threadIdx.x;
  if (i >= n) return;
  float s = 1.0f;
  int e1 = offs[i + 1];
  for (int e = offs[i]; e < e1; ++e)
    s += __half2float(__ushort_as_half((unsigned short)(ecf2[e] & 0xffffu)));
  dinv[i] = rsqrtf(s);
}

// ---------------- MFMA GEMM: Z(chunk layout) = half( dinv[node] * (act(A) @ W) ) ----------------
// Z layout: Z[chunk][n][32] halves, chunk = feature>>5.
template <int ACT>
__device__ __forceinline__ float act_f(float x) {
  if (ACT == 1) return x > 0.f ? x : expm1f(x);
  if (ACT == 2) return 0.5f * x * (1.0f + erff(x * 0.70710678118654752440f));
  return x;
}

template <int ACT, typename AT>
__global__ __launch_bounds__(256) void k_gemm(const AT* __restrict__ A,
                                              const __half* __restrict__ Wt,
                                              const float* __restrict__ dinv,
                                              __half* __restrict__ Z, int n) {
  const int wave = threadIdx.x >> 6;
  const int lane = threadIdx.x & 63;
  const int np = lane & 15;
  const int quad = lane >> 4;
  const int node = blockIdx.x * 64 + wave * 16 + np;
  const int nc = min(node, n - 1);

  half8 b[4];
#pragma unroll
  for (int s = 0; s < 4; ++s) {
    if constexpr (sizeof(AT) == 4) {
      // fp32 x: streamed once, nt-load keeps L2 for Z
      const float* ap = (const float*)A + (size_t)nc * D + s * 32 + quad * 8;
      float4 v0 = ld_nt((const float4*)ap);
      float4 v1 = ld_nt((const float4*)(ap + 4));
      b[s][0] = (_Float16)act_f<ACT>(v0.x); b[s][1] = (_Float16)act_f<ACT>(v0.y);
      b[s][2] = (_Float16)act_f<ACT>(v0.z); b[s][3] = (_Float16)act_f<ACT>(v0.w);
      b[s][4] = (_Float16)act_f<ACT>(v1.x); b[s][5] = (_Float16)act_f<ACT>(v1.y);
      b[s][6] = (_Float16)act_f<ACT>(v1.z); b[s][7] = (_Float16)act_f<ACT>(v1.w);
    } else {
      half8 raw = *(const half8*)((const __half*)A + ((size_t)s * n + nc) * 32 + quad * 8);
#pragma unroll
      for (int t = 0; t < 8; ++t)
        b[s][t] = (_Float16)act_f<ACT>((float)raw[t]);
    }
  }

  floatx4 acc[8];
#pragma unroll
  for (int mt = 0; mt < 8; ++mt) acc[mt] = (floatx4){0.f, 0.f, 0.f, 0.f};

#pragma unroll
  for (int mt = 0; mt < 8; ++mt) {
#pragma unroll
    for (int s = 0; s < 4; ++s) {
      half8 a = *(const half8*)(Wt + (size_t)(mt * 16 + np) * D + s * 32 + quad * 8);
      acc[mt] = __builtin_amdgcn_mfma_f32_16x16x32_f16(a, b[s], acc[mt], 0, 0, 0);
    }
  }

  if (node < n) {
    float dv = dinv[node];   // fold dinv[src] into Z so edge coef is just fp16(w)
#pragma unroll
    for (int mt = 0; mt < 8; ++mt) {
      H4 hv;
      hv.a = __floats2half2_rn(dv * acc[mt][0], dv * acc[mt][1]);
      hv.b = __floats2half2_rn(dv * acc[mt][2], dv * acc[mt][3]);
      int f0 = mt * 16 + quad * 4;
      *(H4*)(Z + ((size_t)(f0 >> 5) * n + node) * 32 + (f0 & 31)) = hv;
    }
  }
}

// -------- aggregation: OUT[c] = dc*( sum w*Z[r] + Z[c] ) + b --------
// 16 lanes/node: 4 edge-subs x 4 j-lanes (16B each). One 64B line per gather.
__device__ __forceinline__ void fmacc8(float* acc, float c, const H8& y) {
  float2 f;
  f = __half22float2(y.h[0]); acc[0] += c * f.x; acc[1] += c * f.y;
  f = __half22float2(y.h[1]); acc[2] += c * f.x; acc[3] += c * f.y;
  f = __half22float2(y.h[2]); acc[4] += c * f.x; acc[5] += c * f.y;
  f = __half22float2(y.h[3]); acc[6] += c * f.x; acc[7] += c * f.y;
}

__device__ __forceinline__ float cdecode(unsigned int u) {
  return __half2float(__ushort_as_half((unsigned short)(u & 0xffffu)));
}

template <int PRELU, typename OutT>
__global__ __launch_bounds__(256) void k_agg(const __half* __restrict__ Z,
                                             const int* __restrict__ offs,
                                             const unsigned int* __restrict__ ecf2,
                                             const float* __restrict__ dinv,
                                             const float* __restrict__ bias,
                                             const float* __restrict__ pw,
                                             OutT* __restrict__ OUT, int n) {
  const int chunk = blockIdx.x & 3;
  const int t = threadIdx.x;
  const int node = (blockIdx.x >> 2) * 16 + (t >> 4);
  const int sub = (t >> 2) & 3;   // 4-way edge split
  const int j = t & 3;            // 16B piece of the 64B chunk
  if (node >= n) return;
  const __half* Zc = Z + (size_t)chunk * n * 32;
  float acc[8] = {0.f, 0.f, 0.f, 0.f, 0.f, 0.f, 0.f, 0.f};
  if (sub == 0) {                 // self term: coefficient 1 (dinv folded into Z)
    H8 zs = *(const H8*)(Zc + (size_t)node * 32 + j * 8);
    fmacc8(acc, 1.0f, zs);
  }
  int e0 = offs[node], e1 = offs[node + 1];
  int e = e0 + sub;
  for (; e + 12 < e1; e += 16) {  // 4 gathers in flight
    unsigned int u0 = ecf2[e],     u1 = ecf2[e + 4];
    unsigned int u2 = ecf2[e + 8], u3 = ecf2[e + 12];
    H8 z0 = *(const H8*)(Zc + (size_t)(u0 >> 16) * 32 + j * 8);
    H8 z1 = *(const H8*)(Zc + (size_t)(u1 >> 16) * 32 + j * 8);
    H8 z2 = *(const H8*)(Zc + (size_t)(u2 >> 16) * 32 + j * 8);
    H8 z3 = *(const H8*)(Zc + (size_t)(u3 >> 16) * 32 + j * 8);
    fmacc8(acc, cdecode(u0), z0);
    fmacc8(acc, cdecode(u1), z1);
    fmacc8(acc, cdecode(u2), z2);
    fmacc8(acc, cdecode(u3), z3);
  }
  for (; e + 4 < e1; e += 8) {    // 2 in flight (common case)
    unsigned int u0 = ecf2[e], u1 = ecf2[e + 4];
    H8 z0 = *(const H8*)(Zc + (size_t)(u0 >> 16) * 32 + j * 8);
    H8 z1 = *(const H8*)(Zc + (size_t)(u1 >> 16) * 32 + j * 8);
    fmacc8(acc, cdecode(u0), z0);
    fmacc8(acc, cdecode(u1), z1);
  }
  for (; e < e1; e += 4) {
    unsigned int u = ecf2[e];
    H8 z = *(const H8*)(Zc + (size_t)(u >> 16) * 32 + j * 8);
    fmacc8(acc, cdecode(u), z);
  }
  // combine 4 subs: lanes differ in bits 2..3
#pragma unroll
  for (int i = 0; i < 8; ++i) {
    acc[i] += __shfl_xor(acc[i], 4, 64);
    acc[i] += __shfl_xor(acc[i], 8, 64);
  }
  // each (sub,j) lane writes 2 features: chunk*32 + j*8 + sub*2 .. +1
  float dc = dinv[node];
  const float* bp = bias + chunk * 32 + j * 8 + sub * 2;
  float o0 = dc * acc[sub * 2 + 0] + bp[0];
  float o1 = dc * acc[sub * 2 + 1] + bp[1];
  if (PRELU) {
    float wv = *pw;
    o0 = o0 >= 0.f ? o0 : wv * o0;
    o1 = o1 >= 0.f ? o1 : wv * o1;
  }
  if constexpr (sizeof(OutT) == 4) {
    st_nt8((float*)OUT + (size_t)node * D + chunk * 32 + j * 8 + sub * 2,
           make_float2(o0, o1));
  } else {
    *(__half2*)((__half*)OUT + ((size_t)chunk * n + node) * 32 + j * 8 + sub * 2) =
        __floats2half2_rn(o0, o1);
  }
}

// ---------------- launch ----------------
extern "C" void kernel_launch(void* const* d_in, const int* in_sizes, int n_in,
                              void* d_out, int out_size, void* d_ws, size_t ws_size,
                              hipStream_t stream) {
  const float* x  = (const float*)d_in[0];
  const int*   ei = (const int*)d_in[1];
  const float* w  = (const float*)d_in[2];
  const float* W1 = (const float*)d_in[3];
  const float* b1 = (const float*)d_in[4];
  const float* W2 = (const float*)d_in[5];
  const float* b2 = (const float*)d_in[6];
  const float* W3 = (const float*)d_in[7];
  const float* b3 = (const float*)d_in[8];
  const float* pw = (const float*)d_in[9];
  const int N = in_sizes[0] / D;
  const int E = in_sizes[2];
  float* out = (float*)d_out;

  char* wsb = (char*)d_ws;
  size_t off = 0;
  auto alloc = [&](size_t bytes) {
    void* p = wsb + off;
    off = (off + bytes + 255) & ~(size_t)255;
    return p;
  };
  float*        dinv = (float*)alloc((size_t)N * 4);
  int*          cnt  = (int*)alloc((size_t)N * 4);
  int*          offs = (int*)alloc((size_t)(N + 1) * 4);
  int*          bsum = (int*)alloc(256 * 4);
  int*          boff = (int*)alloc(256 * 4);
  unsigned int* ecf2 = (unsigned int*)alloc((size_t)E * 4);
  __half*       Wt   = (__half*)alloc((size_t)3 * D * D * 2);
  __half*       Z    = (__half*)alloc((size_t)N * D * 2);
  __half*       h    = (__half*)alloc((size_t)N * D * 2);
  // transient buffers aliased into Z (dead before first GEMM writes Z): 8B/edge < N*D*2
  unsigned int* rcp  = (unsigned int*)Z;
  int*          pos  = (int*)((char*)Z + (size_t)E * 4);

  const int nb = (N + 255) / 256;
  const int eb = (E + 255) / 256;

  hipLaunchKernelGGL(k_init,    dim3(3 + nb), dim3(256), 0, stream, W1, W2, W3, Wt, cnt, N);
  hipLaunchKernelGGL(k_pos,     dim3(eb), dim3(256), 0, stream, ei, cnt, rcp, pos, E, N);
  hipLaunchKernelGGL(k_scan1,   dim3(nb), dim3(256), 0, stream, cnt, offs, bsum, N);
  hipLaunchKernelGGL(k_scan2,   dim3(1),  dim3(256), 0, stream, bsum, boff, nb);
  hipLaunchKernelGGL(k_scan3,   dim3(nb), dim3(256), 0, stream, offs, boff, N, E);
  hipLaunchKernelGGL(k_fill,    dim3(eb), dim3(256), 0, stream, rcp, pos, w, offs, ecf2, E);
  hipLaunchKernelGGL(k_degdinv, dim3(nb), dim3(256), 0, stream, ecf2, offs, dinv, N);

  const int gb = (N + 63) / 64;
  const int ab = 4 * ((N + 15) / 16);

  hipLaunchKernelGGL((k_gemm<0, float>),  dim3(gb), dim3(256), 0, stream, x, Wt,             dinv, Z, N);
  hipLaunchKernelGGL((k_agg<0, __half>),  dim3(ab), dim3(256), 0, stream, Z, offs, ecf2, dinv, b1, pw, h, N);
  hipLaunchKernelGGL((k_gemm<1, __half>), dim3(gb), dim3(256), 0, stream, h, Wt + D * D,     dinv, Z, N);
  hipLaunchKernelGGL((k_agg<0, __half>),  dim3(ab), dim3(256), 0, stream, Z, offs, ecf2, dinv, b2, pw, h, N);
  hipLaunchKernelGGL((k_gemm<2, __half>), dim3(gb), dim3(256), 0, stream, h, Wt + 2 * D * D, dinv, Z, N);
  hipLaunchKernelGGL((k_agg<1, float>),   dim3(ab), dim3(256), 0, stream, Z, offs, ecf2, dinv, b3, pw, out, N);
}

// Round 12
// 303.324 us; speedup vs baseline: 1.1348x; 1.0083x over previous
//
#include <hip/hip_runtime.h>
#include <hip/hip_fp16.h>
#include <math.h>
#include <string.h>

constexpr int D = 128;

struct __align__(16) H8 { __half2 h[4]; };
struct __align__(8)  H4 { __half2 a, b; };

typedef _Float16 half8  __attribute__((ext_vector_type(8)));
typedef float   floatx4 __attribute__((ext_vector_type(4)));
typedef int     i32x4   __attribute__((ext_vector_type(4)));

// ---- non-temporal helpers: ONLY for stream-once data off the critical chain ----
template <typename T>
__device__ __forceinline__ T ld_nt(const T* p) {
  i32x4 v = __builtin_nontemporal_load((const i32x4*)p);
  T r; memcpy(&r, &v, 16); return r;
}
__device__ __forceinline__ void st_nt8(void* p, float2 v) {
  long long t; memcpy(&t, &v, 8);
  __builtin_nontemporal_store(t, (long long*)p);
}
__device__ __forceinline__ void st_nt4(void* p, __half2 v) {
  int t; memcpy(&t, &v, 4);
  __builtin_nontemporal_store(t, (int*)p);
}

// ---------------- preprocessing ----------------

__device__ __forceinline__ int detect64(const int* __restrict__ ei) {
  int z = 0;
#pragma unroll
  for (int i = 0; i < 8; ++i) z |= ei[2 * i + 1];
  return (z == 0) ? 1 : 0;
}

__device__ __forceinline__ void load_edge(const int* __restrict__ ei, int e, int nE,
                                          int m64, int n, int& r, int& c) {
  if (m64) { r = ei[2 * (size_t)e]; c = ei[2 * ((size_t)nE + e)]; }
  else     { r = ei[(size_t)e];     c = ei[(size_t)nE + e]; }
  r = min(max(r, 0), n - 1);
  c = min(max(c, 0), n - 1);
}

// blocks [0,3): transpose W1/W2/W3 fp32 [k][n] -> Wt fp16 [n][k]. blocks [3..): zero cnt.
__global__ void k_init(const float* __restrict__ W1, const float* __restrict__ W2,
                       const float* __restrict__ W3, __half* __restrict__ Wt,
                       int* __restrict__ cnt, int n) {
  __shared__ float s[128][129];
  int tid = threadIdx.x;
  if (blockIdx.x >= 3) {
    int i = (blockIdx.x - 3) * 256 + tid;
    if (i < n) cnt[i] = 0;
    return;
  }
  const float* W = blockIdx.x == 0 ? W1 : (blockIdx.x == 1 ? W2 : W3);
  __half* o = Wt + (size_t)blockIdx.x * D * D;
#pragma unroll
  for (int i = 0; i < 16; ++i) {
    int flat = i * 1024 + tid * 4;
    int k = flat >> 7;
    int nn = flat & 127;
    float4 v = *(const float4*)(W + (size_t)k * D + nn);
    s[k][nn] = v.x; s[k][nn + 1] = v.y; s[k][nn + 2] = v.z; s[k][nn + 3] = v.w;
  }
  __syncthreads();
#pragma unroll
  for (int i = 0; i < 8; ++i) {
    int flat = i * 256 + tid;
    int nn = flat >> 4;
    int k0 = (flat & 15) * 8;
    H8 hv;
#pragma unroll
    for (int t = 0; t < 4; ++t)
      hv.h[t] = __floats2half2_rn(s[k0 + 2 * t][nn], s[k0 + 2 * t + 1][nn]);
    *(H8*)(o + (size_t)nn * D + k0) = hv;
  }
}

// ONE atomic per edge; packed (r<<16)|c; rank stored for atomic-free fill.
__global__ void k_pos(const int* __restrict__ ei, int* __restrict__ cnt,
                      unsigned int* __restrict__ rcp, int* __restrict__ pos,
                      int nE, int n) {
  int e = blockIdx.x * blockDim.x + threadIdx.x;
  if (e >= nE) return;
  int m64 = detect64(ei);
  int r, c;
  load_edge(ei, e, nE, m64, n, r, c);
  rcp[e] = ((unsigned int)r << 16) | (unsigned int)c;
  pos[e] = atomicAdd(&cnt[c], 1);
}

// Parallel 3-kernel exclusive scan.
__global__ void k_scan1(const int* __restrict__ cnt, int* __restrict__ offs,
                        int* __restrict__ bsum, int n) {
  __shared__ int s[256];
  int t = threadIdx.x;
  int i = blockIdx.x * 256 + t;
  int v = (i < n) ? cnt[i] : 0;
  s[t] = v;
  __syncthreads();
  for (int off = 1; off < 256; off <<= 1) {
    int x = 0;
    if (t >= off) x = s[t - off];
    __syncthreads();
    if (t >= off) s[t] += x;
    __syncthreads();
  }
  if (i < n) offs[i] = s[t] - v;
  if (t == 255) bsum[blockIdx.x] = s[255];
}

__global__ void k_scan2(const int* __restrict__ bsum, int* __restrict__ boff, int nb) {
  __shared__ int s[256];
  int t = threadIdx.x;
  int v = (t < nb) ? bsum[t] : 0;
  s[t] = v;
  __syncthreads();
  for (int off = 1; off < 256; off <<= 1) {
    int x = 0;
    if (t >= off) x = s[t - off];
    __syncthreads();
    if (t >= off) s[t] += x;
    __syncthreads();
  }
  if (t < nb) boff[t] = s[t] - v;
}

__global__ void k_scan3(int* __restrict__ offs, const int* __restrict__ boff, int n, int nE) {
  int i = blockIdx.x * 256 + threadIdx.x;
  if (i < n) offs[i] += boff[blockIdx.x];
  if (i == 0) offs[n] = nE;
}

// Atomic-free CSR fill writing the FINAL packed edge record: (src<<16) | fp16(w).
__global__ void k_fill(const unsigned int* __restrict__ rcp, const int* __restrict__ pos,
                       const float* __restrict__ w, const int* __restrict__ offs,
                       unsigned int* __restrict__ ecf2, int nE) {
  int e = blockIdx.x * blockDim.x + threadIdx.x;
  if (e >= nE) return;
  unsigned int p = rcp[e];
  int idx = offs[p & 0xffffu] + pos[e];
  ecf2[idx] = (p & 0xffff0000u) |
              (unsigned int)__half_as_ushort(__float2half_rn(w[e]));
}

// deg[c] = 1 (self loop) + sum fp16(w) over CSR row; dinv = rsqrt(deg).
__global__ void k_degdinv(const unsigned int* __restrict__ ecf2, const int* __restrict__ offs,
                          float* __restrict__ dinv, int n) {
  int i = blockIdx.x * blockDim.x + threadIdx.x;
  if (i >= n) return;
  float s = 1.0f;
  int e1 = offs[i + 1];
  for (int e = offs[i]; e < e1; ++e)
    s += __half2float(__ushort_as_half((unsigned short)(ecf2[e] & 0xffffu)));
  dinv[i] = rsqrtf(s);
}

// ---------------- MFMA GEMM: Z(chunk layout) = half( dinv[node] * (act(A) @ W) ) ----------------
template <int ACT>
__device__ __forceinline__ float act_f(float x) {
  if (ACT == 1) return x > 0.f ? x : expm1f(x);
  if (ACT == 2) return 0.5f * x * (1.0f + erff(x * 0.70710678118654752440f));
  return x;
}

template <int ACT, typename AT>
__global__ __launch_bounds__(256) void k_gemm(const AT* __restrict__ A,
                                              const __half* __restrict__ Wt,
                                              const float* __restrict__ dinv,
                                              __half* __restrict__ Z, int n) {
  const int wave = threadIdx.x >> 6;
  const int lane = threadIdx.x & 63;
  const int np = lane & 15;
  const int quad = lane >> 4;
  const int node = blockIdx.x * 64 + wave * 16 + np;
  const int nc = min(node, n - 1);

  half8 b[4];
#pragma unroll
  for (int s = 0; s < 4; ++s) {
    if constexpr (sizeof(AT) == 4) {
      // fp32 x: streamed once, nt keeps L2 for Z
      const float* ap = (const float*)A + (size_t)nc * D + s * 32 + quad * 8;
      float4 v0 = ld_nt((const float4*)ap);
      float4 v1 = ld_nt((const float4*)(ap + 4));
      b[s][0] = (_Float16)act_f<ACT>(v0.x); b[s][1] = (_Float16)act_f<ACT>(v0.y);
      b[s][2] = (_Float16)act_f<ACT>(v0.z); b[s][3] = (_Float16)act_f<ACT>(v0.w);
      b[s][4] = (_Float16)act_f<ACT>(v1.x); b[s][5] = (_Float16)act_f<ACT>(v1.y);
      b[s][6] = (_Float16)act_f<ACT>(v1.z); b[s][7] = (_Float16)act_f<ACT>(v1.w);
    } else {
      // h: nt-stored by agg (streamed), nt-read here -> L2 reserved for Z
      half8 raw = ld_nt((const half8*)((const __half*)A + ((size_t)s * n + nc) * 32 + quad * 8));
#pragma unroll
      for (int t = 0; t < 8; ++t)
        b[s][t] = (_Float16)act_f<ACT>((float)raw[t]);
    }
  }

  floatx4 acc[8];
#pragma unroll
  for (int mt = 0; mt < 8; ++mt) acc[mt] = (floatx4){0.f, 0.f, 0.f, 0.f};

#pragma unroll
  for (int mt = 0; mt < 8; ++mt) {
#pragma unroll
    for (int s = 0; s < 4; ++s) {
      half8 a = *(const half8*)(Wt + (size_t)(mt * 16 + np) * D + s * 32 + quad * 8);
      acc[mt] = __builtin_amdgcn_mfma_f32_16x16x32_f16(a, b[s], acc[mt], 0, 0, 0);
    }
  }

  if (node < n) {
    float dv = dinv[node];   // fold dinv[src] into Z so edge coef is just fp16(w)
#pragma unroll
    for (int mt = 0; mt < 8; ++mt) {
      H4 hv;
      hv.a = __floats2half2_rn(dv * acc[mt][0], dv * acc[mt][1]);
      hv.b = __floats2half2_rn(dv * acc[mt][2], dv * acc[mt][3]);
      int f0 = mt * 16 + quad * 4;
      // NORMAL store: Z is the gather target, must stay L2-resident
      *(H4*)(Z + ((size_t)(f0 >> 5) * n + node) * 32 + (f0 & 31)) = hv;
    }
  }
}

// -------- aggregation: OUT[c] = dc*( sum w*Z[r] + Z[c] ) + b --------
// 16 lanes/node: 4 edge-subs x 4 j-lanes. Sub s takes CONTIGUOUS edges
// [e0+4s+16t, +4): one batch of 4 adjacent edge words -> 4 independent gathers
// -> 2 serial memory rounds for degree<=16 (was 3-4 with stride-4 interleave).
// OOB slots masked branchlessly (idx->0, coef->0; loads land in ws slack).
__device__ __forceinline__ void fmacc8(float* acc, float c, const H8& y) {
  float2 f;
  f = __half22float2(y.h[0]); acc[0] += c * f.x; acc[1] += c * f.y;
  f = __half22float2(y.h[1]); acc[2] += c * f.x; acc[3] += c * f.y;
  f = __half22float2(y.h[2]); acc[4] += c * f.x; acc[5] += c * f.y;
  f = __half22float2(y.h[3]); acc[6] += c * f.x; acc[7] += c * f.y;
}

__device__ __forceinline__ float cdecode(unsigned int u) {
  return __half2float(__ushort_as_half((unsigned short)(u & 0xffffu)));
}

template <int PRELU, typename OutT>
__global__ __launch_bounds__(256) void k_agg(const __half* __restrict__ Z,
                                             const int* __restrict__ offs,
                                             const unsigned int* __restrict__ ecf2,
                                             const float* __restrict__ dinv,
                                             const float* __restrict__ bias,
                                             const float* __restrict__ pw,
                                             OutT* __restrict__ OUT, int n) {
  const int chunk = blockIdx.x & 3;
  const int t = threadIdx.x;
  const int node = (blockIdx.x >> 2) * 16 + (t >> 4);
  const int sub = (t >> 2) & 3;   // 4-way contiguous edge split
  const int j = t & 3;            // 16B piece of the 64B chunk
  if (node >= n) return;
  const __half* Zc = Z + (size_t)chunk * n * 32;
  float acc[8] = {0.f, 0.f, 0.f, 0.f, 0.f, 0.f, 0.f, 0.f};
  if (sub == 0) {                 // self term: coefficient 1 (dinv folded into Z)
    H8 zs = *(const H8*)(Zc + (size_t)node * 32 + j * 8);
    fmacc8(acc, 1.0f, zs);
  }
  int e0 = offs[node], e1 = offs[node + 1];
  for (int base = e0 + sub * 4; base < e1; base += 16) {
    // 4 adjacent edge words (1-2 cache lines), issued together
    unsigned int u0 = ecf2[base];
    unsigned int u1 = ecf2[base + 1];
    unsigned int u2 = ecf2[base + 2];
    unsigned int u3 = ecf2[base + 3];
    bool k1 = base + 1 < e1, k2 = base + 2 < e1, k3 = base + 3 < e1;
    int i0 = (int)(u0 >> 16);
    int i1 = k1 ? (int)(u1 >> 16) : 0;
    int i2 = k2 ? (int)(u2 >> 16) : 0;
    int i3 = k3 ? (int)(u3 >> 16) : 0;
    float c0 = cdecode(u0);
    float c1 = k1 ? cdecode(u1) : 0.f;
    float c2 = k2 ? cdecode(u2) : 0.f;
    float c3 = k3 ? cdecode(u3) : 0.f;
    H8 z0 = *(const H8*)(Zc + (size_t)i0 * 32 + j * 8);
    H8 z1 = *(const H8*)(Zc + (size_t)i1 * 32 + j * 8);
    H8 z2 = *(const H8*)(Zc + (size_t)i2 * 32 + j * 8);
    H8 z3 = *(const H8*)(Zc + (size_t)i3 * 32 + j * 8);
    fmacc8(acc, c0, z0);
    fmacc8(acc, c1, z1);
    fmacc8(acc, c2, z2);
    fmacc8(acc, c3, z3);
  }
  // combine 4 subs: lanes differ in bits 2..3
#pragma unroll
  for (int i = 0; i < 8; ++i) {
    acc[i] += __shfl_xor(acc[i], 4, 64);
    acc[i] += __shfl_xor(acc[i], 8, 64);
  }
  // each (sub,j) lane writes 2 features: chunk*32 + j*8 + sub*2 .. +1
  float dc = dinv[node];
  const float* bp = bias + chunk * 32 + j * 8 + sub * 2;
  float o0 = dc * acc[sub * 2 + 0] + bp[0];
  float o1 = dc * acc[sub * 2 + 1] + bp[1];
  if (PRELU) {
    float wv = *pw;
    o0 = o0 >= 0.f ? o0 : wv * o0;
    o1 = o1 >= 0.f ? o1 : wv * o1;
  }
  if constexpr (sizeof(OutT) == 4) {
    st_nt8((float*)OUT + (size_t)node * D + chunk * 32 + j * 8 + sub * 2,
           make_float2(o0, o1));
  } else {
    // h streamed by next GEMM: nt-store protects L2 for Z during this agg
    st_nt4((__half*)OUT + ((size_t)chunk * n + node) * 32 + j * 8 + sub * 2,
           __floats2half2_rn(o0, o1));
  }
}

// ---------------- launch ----------------
extern "C" void kernel_launch(void* const* d_in, const int* in_sizes, int n_in,
                              void* d_out, int out_size, void* d_ws, size_t ws_size,
                              hipStream_t stream) {
  const float* x  = (const float*)d_in[0];
  const int*   ei = (const int*)d_in[1];
  const float* w  = (const float*)d_in[2];
  const float* W1 = (const float*)d_in[3];
  const float* b1 = (const float*)d_in[4];
  const float* W2 = (const float*)d_in[5];
  const float* b2 = (const float*)d_in[6];
  const float* W3 = (const float*)d_in[7];
  const float* b3 = (const float*)d_in[8];
  const float* pw = (const float*)d_in[9];
  const int N = in_sizes[0] / D;
  const int E = in_sizes[2];
  float* out = (float*)d_out;

  char* wsb = (char*)d_ws;
  size_t off = 0;
  auto alloc = [&](size_t bytes) {
    void* p = wsb + off;
    off = (off + bytes + 255) & ~(size_t)255;
    return p;
  };
  float*        dinv = (float*)alloc((size_t)N * 4);
  int*          cnt  = (int*)alloc((size_t)N * 4);
  int*          offs = (int*)alloc((size_t)(N + 1) * 4);
  int*          bsum = (int*)alloc(256 * 4);
  int*          boff = (int*)alloc(256 * 4);
  unsigned int* ecf2 = (unsigned int*)alloc((size_t)E * 4 + 64);  // +slack for OOB batch reads
  __half*       Wt   = (__half*)alloc((size_t)3 * D * D * 2);
  __half*       Z    = (__half*)alloc((size_t)N * D * 2);
  __half*       h    = (__half*)alloc((size_t)N * D * 2);
  // transient buffers aliased into Z (dead before first GEMM writes Z): 8B/edge < N*D*2
  unsigned int* rcp  = (unsigned int*)Z;
  int*          pos  = (int*)((char*)Z + (size_t)E * 4);

  const int nb = (N + 255) / 256;
  const int eb = (E + 255) / 256;

  hipLaunchKernelGGL(k_init,    dim3(3 + nb), dim3(256), 0, stream, W1, W2, W3, Wt, cnt, N);
  hipLaunchKernelGGL(k_pos,     dim3(eb), dim3(256), 0, stream, ei, cnt, rcp, pos, E, N);
  hipLaunchKernelGGL(k_scan1,   dim3(nb), dim3(256), 0, stream, cnt, offs, bsum, N);
  hipLaunchKernelGGL(k_scan2,   dim3(1),  dim3(256), 0, stream, bsum, boff, nb);
  hipLaunchKernelGGL(k_scan3,   dim3(nb), dim3(256), 0, stream, offs, boff, N, E);
  hipLaunchKernelGGL(k_fill,    dim3(eb), dim3(256), 0, stream, rcp, pos, w, offs, ecf2, E);
  hipLaunchKernelGGL(k_degdinv, dim3(nb), dim3(256), 0, stream, ecf2, offs, dinv, N);

  const int gb = (N + 63) / 64;
  const int ab = 4 * ((N + 15) / 16);

  hipLaunchKernelGGL((k_gemm<0, float>),  dim3(gb), dim3(256), 0, stream, x, Wt,             dinv, Z, N);
  hipLaunchKernelGGL((k_agg<0, __half>),  dim3(ab), dim3(256), 0, stream, Z, offs, ecf2, dinv, b1, pw, h, N);
  hipLaunchKernelGGL((k_gemm<1, __half>), dim3(gb), dim3(256), 0, stream, h, Wt + D * D,     dinv, Z, N);
  hipLaunchKernelGGL((k_agg<0, __half>),  dim3(ab), dim3(256), 0, stream, Z, offs, ecf2, dinv, b2, pw, h, N);
  hipLaunchKernelGGL((k_gemm<2, __half>), dim3(gb), dim3(256), 0, stream, h, Wt + 2 * D * D, dinv, Z, N);
  hipLaunchKernelGGL((k_agg<1, float>),   dim3(ab), dim3(256), 0, stream, Z, offs, ecf2, dinv, b3, pw, out, N);
}